// Round 2
// baseline (197.532 us; speedup 1.0000x reference)
//
#include <hip/hip_runtime.h>
#include <hip/hip_bf16.h>

#define N_    16
#define V_    5023
#define F_    9976
#define HW_   (512*512)
#define NV_   (N_*V_)      // 80368
#define NPIX_ (N_*HW_)     // 4194304

// Kernel 1: single block. Reduce min/max of tv[:,:,2] (fp32), then write
// zval[i] = (zmax - z_i) / (zmax - zmin) as f32 into workspace.
//
// Note on the reference algebra: z = -(z_col - z_col.min()) repeated 3x;
// z -= z.min(); z /= z.max()  collapses to  (zmax - z_i) / (zmax - zmin)
// with zmin/zmax over all N*V z-coords, identical across the 3 channels.
__global__ __launch_bounds__(1024) void zval_kernel(
        const float* __restrict__ tv,   // (N,V,3) f32
        float* __restrict__ zval) {     // (N*V) f32 out
    __shared__ float smin[16], smax[16], sfinal[2];
    const int tid = threadIdx.x;
    float vmin = 1e30f, vmax = -1e30f;
    for (int i = tid; i < NV_; i += 1024) {
        float z = tv[3*i + 2];
        vmin = fminf(vmin, z);
        vmax = fmaxf(vmax, z);
    }
#pragma unroll
    for (int off = 32; off > 0; off >>= 1) {
        vmin = fminf(vmin, __shfl_down(vmin, off));
        vmax = fmaxf(vmax, __shfl_down(vmax, off));
    }
    if ((tid & 63) == 0) { smin[tid >> 6] = vmin; smax[tid >> 6] = vmax; }
    __syncthreads();
    if (tid == 0) {
        float m = smin[0], M = smax[0];
        for (int w = 1; w < 16; ++w) { m = fminf(m, smin[w]); M = fmaxf(M, smax[w]); }
        sfinal[0] = m; sfinal[1] = M;
    }
    __syncthreads();
    const float zmin = sfinal[0], zmax = sfinal[1];
    const float inv = 1.0f / (zmax - zmin);
    for (int i = tid; i < NV_; i += 1024) {
        float z = tv[3*i + 2];
        zval[i] = (zmax - z) * inv;
    }
}

// Kernel 2: 2 pixels per thread.
// out[pix] = pix_to_face<0 ? 0 : sum_c bary[pix,c] * zval[nn, faces[ff,c]]
__global__ __launch_bounds__(256) void render_kernel(
        const int*    __restrict__ p2f,    // (NPIX) int32
        const float*  __restrict__ bary,   // (NPIX,3) f32
        const int*    __restrict__ faces,  // (F,3) int32
        const float*  __restrict__ zval,   // (N*V) f32
        float*        __restrict__ out) {  // (NPIX) f32
    const int t = blockIdx.x * blockDim.x + threadIdx.x;   // pixels 2t, 2t+1
    const int2 pp = ((const int2*)p2f)[t];
    // 24 B of bary for the two pixels as three float2 (8B-aligned)
    const float2 b0 = ((const float2*)bary)[3*t + 0];  // p0.c0, p0.c1
    const float2 b1 = ((const float2*)bary)[3*t + 1];  // p0.c2, p1.c0
    const float2 b2 = ((const float2*)bary)[3*t + 2];  // p1.c1, p1.c2

    float r0 = 0.0f, r1 = 0.0f;
    if (pp.x >= 0) {
        const int nn = pp.x / F_;
        const int ff = pp.x - nn * F_;
        const int v0 = faces[3*ff], v1 = faces[3*ff + 1], v2 = faces[3*ff + 2];
        const float* zr = zval + nn * V_;
        r0 = b0.x * zr[v0] + b0.y * zr[v1] + b1.x * zr[v2];
    }
    if (pp.y >= 0) {
        const int nn = pp.y / F_;
        const int ff = pp.y - nn * F_;
        const int v0 = faces[3*ff], v1 = faces[3*ff + 1], v2 = faces[3*ff + 2];
        const float* zr = zval + nn * V_;
        r1 = b1.y * zr[v0] + b2.x * zr[v1] + b2.y * zr[v2];
    }
    float2 o; o.x = r0; o.y = r1;
    ((float2*)out)[t] = o;
}

extern "C" void kernel_launch(void* const* d_in, const int* in_sizes, int n_in,
                              void* d_out, int out_size, void* d_ws, size_t ws_size,
                              hipStream_t stream) {
    const float* tv    = (const float*)d_in[0];  // f32 (N,V,3)
    const float* bary  = (const float*)d_in[1];  // f32 (N,H,W,1,3)
    const int*   faces = (const int*)d_in[2];    // int32 (F,3)
    const int*   p2f   = (const int*)d_in[3];    // int32 (N,H,W,1)
    float* zval = (float*)d_ws;                  // 321,472 B scratch

    zval_kernel<<<1, 1024, 0, stream>>>(tv, zval);
    render_kernel<<<NPIX_ / 2 / 256, 256, 0, stream>>>(
        p2f, bary, faces, zval, (float*)d_out);
}

// Round 3
// 129.140 us; speedup vs baseline: 1.5296x; 1.5296x over previous
//
#include <hip/hip_runtime.h>
#include <hip/hip_bf16.h>

#define N_    16
#define V_    5023
#define F_    9976
#define HW_   (512*512)
#define NV_   (N_*V_)      // 80368
#define NF_   (N_*F_)      // 159616
#define NPIX_ (N_*HW_)     // 4194304

// ---- ordered-float <-> uint encoding (monotone, works for mixed signs) ----
__device__ __forceinline__ unsigned int encf(float f) {
    unsigned int b = __float_as_uint(f);
    return (b & 0x80000000u) ? ~b : (b | 0x80000000u);
}
__device__ __forceinline__ float decf(unsigned int e) {
    unsigned int b = (e & 0x80000000u) ? (e & 0x7FFFFFFFu) : ~e;
    return __uint_as_float(b);
}

// hdr[0] = running encoded max (atomicMax), hdr[1] = running encoded min (atomicMin)
__global__ void init_kernel(unsigned int* __restrict__ hdr) {
    hdr[0] = 0u;
    hdr[1] = 0xFFFFFFFFu;
}

// Parallel min/max over tv[:,:,2]. 128 blocks x 256; block-reduce then 1 atomic pair.
__global__ __launch_bounds__(256) void minmax_kernel(
        const float* __restrict__ tv, unsigned int* __restrict__ hdr) {
    float vmin = 1e30f, vmax = -1e30f;
    for (int i = blockIdx.x * 256 + threadIdx.x; i < NV_; i += gridDim.x * 256) {
        float z = tv[3*i + 2];
        vmin = fminf(vmin, z);
        vmax = fmaxf(vmax, z);
    }
#pragma unroll
    for (int off = 32; off > 0; off >>= 1) {
        vmin = fminf(vmin, __shfl_down(vmin, off));
        vmax = fmaxf(vmax, __shfl_down(vmax, off));
    }
    __shared__ float smin[4], smax[4];
    const int lane = threadIdx.x & 63, w = threadIdx.x >> 6;
    if (lane == 0) { smin[w] = vmin; smax[w] = vmax; }
    __syncthreads();
    if (threadIdx.x == 0) {
        float m = fminf(fminf(smin[0], smin[1]), fminf(smin[2], smin[3]));
        float M = fmaxf(fmaxf(smax[0], smax[1]), fmaxf(smax[2], smax[3]));
        atomicMin(&hdr[1], encf(m));
        atomicMax(&hdr[0], encf(M));
    }
}

// Build face_attr[n*F+f] = {zval(v0), zval(v1), zval(v2), 0} directly from tv.
// zval(v) = (zmax - tv[n,v,2]) / (zmax - zmin). Table = 2.55 MB, L2-resident.
__global__ __launch_bounds__(256) void table_kernel(
        const float* __restrict__ tv, const int* __restrict__ faces,
        const unsigned int* __restrict__ hdr, float4* __restrict__ table) {
    const int f = blockIdx.x * 256 + threadIdx.x;
    if (f >= F_) return;
    const int n = blockIdx.y;
    const float zmax = decf(hdr[0]);
    const float inv  = 1.0f / (zmax - decf(hdr[1]));
    const int v0 = faces[3*f], v1 = faces[3*f + 1], v2 = faces[3*f + 2];
    const float* base = tv + n * (V_ * 3);
    float4 o;
    o.x = (zmax - base[3*v0 + 2]) * inv;
    o.y = (zmax - base[3*v1 + 2]) * inv;
    o.z = (zmax - base[3*v2 + 2]) * inv;
    o.w = 0.0f;
    table[n * F_ + f] = o;
}

// Render: 2 pixels/thread, ONE scattered float4 gather per valid pixel.
__global__ __launch_bounds__(256) void render_kernel(
        const int*    __restrict__ p2f,    // (NPIX) int32
        const float*  __restrict__ bary,   // (NPIX,3) f32
        const float4* __restrict__ table,  // (N*F) f32x4
        float*        __restrict__ out) {  // (NPIX) f32
    const int t = blockIdx.x * 256 + threadIdx.x;
    const int2 pp = ((const int2*)p2f)[t];
    const float2 b0 = ((const float2*)bary)[3*t + 0];  // p0.c0, p0.c1
    const float2 b1 = ((const float2*)bary)[3*t + 1];  // p0.c2, p1.c0
    const float2 b2 = ((const float2*)bary)[3*t + 2];  // p1.c1, p1.c2
    float r0 = 0.0f, r1 = 0.0f;
    if (pp.x >= 0) {
        const float4 a = table[pp.x];
        r0 = b0.x * a.x + b0.y * a.y + b1.x * a.z;
    }
    if (pp.y >= 0) {
        const float4 a = table[pp.y];
        r1 = b1.y * a.x + b2.x * a.y + b2.y * a.z;
    }
    float2 o; o.x = r0; o.y = r1;
    ((float2*)out)[t] = o;
}

// ---------- fallback path (small ws): zval table + 6-gather render ----------
__global__ __launch_bounds__(256) void zval_build_kernel(
        const float* __restrict__ tv, const unsigned int* __restrict__ hdr,
        float* __restrict__ zval) {
    const int i = blockIdx.x * 256 + threadIdx.x;
    if (i >= NV_) return;
    const float zmax = decf(hdr[0]);
    const float inv  = 1.0f / (zmax - decf(hdr[1]));
    zval[i] = (zmax - tv[3*i + 2]) * inv;
}

__global__ __launch_bounds__(256) void render_fallback_kernel(
        const int* __restrict__ p2f, const float* __restrict__ bary,
        const int* __restrict__ faces, const float* __restrict__ zval,
        float* __restrict__ out) {
    const int t = blockIdx.x * 256 + threadIdx.x;
    const int2 pp = ((const int2*)p2f)[t];
    const float2 b0 = ((const float2*)bary)[3*t + 0];
    const float2 b1 = ((const float2*)bary)[3*t + 1];
    const float2 b2 = ((const float2*)bary)[3*t + 2];
    float r0 = 0.0f, r1 = 0.0f;
    if (pp.x >= 0) {
        const int nn = pp.x / F_, ff = pp.x - nn * F_;
        const float* zr = zval + nn * V_;
        r0 = b0.x * zr[faces[3*ff]] + b0.y * zr[faces[3*ff+1]] + b1.x * zr[faces[3*ff+2]];
    }
    if (pp.y >= 0) {
        const int nn = pp.y / F_, ff = pp.y - nn * F_;
        const float* zr = zval + nn * V_;
        r1 = b1.y * zr[faces[3*ff]] + b2.x * zr[faces[3*ff+1]] + b2.y * zr[faces[3*ff+2]];
    }
    float2 o; o.x = r0; o.y = r1;
    ((float2*)out)[t] = o;
}

extern "C" void kernel_launch(void* const* d_in, const int* in_sizes, int n_in,
                              void* d_out, int out_size, void* d_ws, size_t ws_size,
                              hipStream_t stream) {
    const float* tv    = (const float*)d_in[0];  // f32 (N,V,3)
    const float* bary  = (const float*)d_in[1];  // f32 (N,H,W,1,3)
    const int*   faces = (const int*)d_in[2];    // int32 (F,3)
    const int*   p2f   = (const int*)d_in[3];    // int32 (N,H,W,1)
    float* outp = (float*)d_out;

    unsigned int* hdr = (unsigned int*)d_ws;     // 16 B header (min/max atomics)

    init_kernel<<<1, 1, 0, stream>>>(hdr);
    minmax_kernel<<<128, 256, 0, stream>>>(tv, hdr);

    const size_t table_need = 16 + (size_t)NF_ * 16;   // ~2.55 MB
    if (ws_size >= table_need) {
        float4* table = (float4*)((char*)d_ws + 16);
        dim3 tgrid((F_ + 255) / 256, N_);
        table_kernel<<<tgrid, 256, 0, stream>>>(tv, faces, hdr, table);
        render_kernel<<<NPIX_ / 2 / 256, 256, 0, stream>>>(p2f, bary, table, outp);
    } else {
        float* zval = (float*)((char*)d_ws + 16);      // 321 KB
        zval_build_kernel<<<(NV_ + 255) / 256, 256, 0, stream>>>(tv, hdr, zval);
        render_fallback_kernel<<<NPIX_ / 2 / 256, 256, 0, stream>>>(
            p2f, bary, faces, zval, outp);
    }
}